// Round 1
// baseline (1085.373 us; speedup 1.0000x reference)
//
#include <hip/hip_runtime.h>
#include <stdint.h>

#define S_TOK 8192
#define HID 2880
#define NQ 64
#define NKV 8
#define HD 64
#define QKV_N 5120   // 4096 q + 512 k + 512 v
#define NO_PAD 2944  // 2880 padded to multiple of 128

typedef __attribute__((ext_vector_type(8))) __bf16 bf16x8;
typedef __attribute__((ext_vector_type(8))) short short8;
typedef __attribute__((ext_vector_type(4))) float f32x4;

__device__ __forceinline__ unsigned short f2bf(float f) {
  unsigned int u = __builtin_bit_cast(unsigned int, f);
  u += 0x7fff + ((u >> 16) & 1);
  return (unsigned short)(u >> 16);
}
__device__ __forceinline__ float bf2f(unsigned short h) {
  unsigned int u = ((unsigned int)h) << 16;
  return __builtin_bit_cast(float, u);
}

__device__ __forceinline__ void async_lds16(const void* g, void* l) {
  __builtin_amdgcn_global_load_lds(
      (const __attribute__((address_space(1))) unsigned int*)g,
      (__attribute__((address_space(3))) unsigned int*)l, 16, 0, 0);
}

// ---------------- elementwise f32 -> bf16 ----------------
__global__ __launch_bounds__(256) void cvt_bf16_kernel(
    const float* __restrict__ src, unsigned short* __restrict__ dst) {
  size_t i = ((size_t)blockIdx.x * 256 + threadIdx.x) * 8;
  float4 a = *(const float4*)(src + i);
  float4 b = *(const float4*)(src + i + 4);
  union { unsigned short u[8]; uint4 v; } o;
  o.u[0] = f2bf(a.x); o.u[1] = f2bf(a.y); o.u[2] = f2bf(a.z); o.u[3] = f2bf(a.w);
  o.u[4] = f2bf(b.x); o.u[5] = f2bf(b.y); o.u[6] = f2bf(b.z); o.u[7] = f2bf(b.w);
  *(uint4*)(dst + i) = o.v;
}

// ------------- transpose + convert: src[R][C] f32 -> dst[(c+rowOff)][R] bf16 -------------
__global__ __launch_bounds__(256) void transpose_cvt(
    const float* __restrict__ src, unsigned short* __restrict__ dst,
    int R, int C, int rowOff) {
  __shared__ float tile[32][33];
  int tx = threadIdx.x, ty = threadIdx.y;  // block (32,8)
  int c0 = blockIdx.x * 32, r0 = blockIdx.y * 32;
#pragma unroll
  for (int i = 0; i < 4; ++i)
    tile[ty + i * 8][tx] = src[(size_t)(r0 + ty + i * 8) * C + c0 + tx];
  __syncthreads();
#pragma unroll
  for (int i = 0; i < 4; ++i)
    dst[(size_t)(c0 + ty + i * 8 + rowOff) * R + r0 + tx] = f2bf(tile[tx][ty + i * 8]);
}

// ---------------- in-place RoPE on q (heads 0..63) and k (heads 64..71) ----------------
__global__ __launch_bounds__(256) void rope_kernel(
    unsigned short* __restrict__ qkv, const int* __restrict__ positions) {
  int gid = blockIdx.x * 256 + threadIdx.x;   // 8192*72*32 total
  int d = gid & 31;
  int rest = gid >> 5;
  int head = rest % 72;
  int t = rest / 72;
  unsigned short* p = qkv + (size_t)t * QKV_N + head * 64;
  float x1 = bf2f(p[d]);
  float x2 = bf2f(p[d + 32]);
  float pos = (float)positions[t];
  // inv_freq = 150000^(-2d/64) = 2^(-d * 2/64 * log2(150000))
  float inv = exp2f(-0.5373313430f * (float)d);
  float ang = pos * inv;
  float s, c;
  __sincosf(ang, &s, &c);
  // use accurate versions to track the fp32 reference closely
  s = sinf(ang); c = cosf(ang);
  p[d] = f2bf(x1 * c - x2 * s);
  p[d + 32] = f2bf(x2 * c + x1 * s);
}

// ---------------- 128x128-tile bf16 GEMM, BT input (rows = N, cols = K) ----------------
// MODE 0: qkv projection -> bf16 out, 3-segment bias (bq|bk|bv), N=5120
// MODE 1: out projection -> f32 out + bo, valid cols < 2880 (N padded 2944)
template <int MODE>
__global__ __launch_bounds__(256) void gemm_bt(
    const unsigned short* __restrict__ A, const unsigned short* __restrict__ BT,
    void* __restrict__ Cout, int K,
    const float* __restrict__ b0, const float* __restrict__ b1,
    const float* __restrict__ b2) {
  __shared__ unsigned short As[128 * 64];
  __shared__ unsigned short Bs[128 * 64];
  const int tid = threadIdx.x;
  const int wave = tid >> 6, lane = tid & 63;
  const int quad = lane >> 4, ml = lane & 15;
  const int wy = wave >> 1, wx = wave & 1;
  const int m0 = blockIdx.y * 128, n0 = blockIdx.x * 128;

  f32x4 zero = {0.f, 0.f, 0.f, 0.f};
  f32x4 acc[4][4];
#pragma unroll
  for (int i = 0; i < 4; ++i)
#pragma unroll
    for (int j = 0; j < 4; ++j) acc[i][j] = zero;

  const int srow = tid >> 3;            // 0..31 (row within 128 per chunk of 8 threads)
  const int scol = (tid & 7) << 3;      // 0,8,..,56

  for (int k0 = 0; k0 < K; k0 += 64) {
    const unsigned short* Ag = A + (size_t)m0 * K + k0;
    const unsigned short* Bg = BT + (size_t)n0 * K + k0;
#pragma unroll
    for (int i = 0; i < 4; ++i) {
      int s = tid + i * 256;
      int row = s >> 3, c = (s & 7) << 3;
      async_lds16(Ag + (size_t)row * K + c, &As[s * 8]);
      async_lds16(Bg + (size_t)row * K + c, &Bs[s * 8]);
    }
    __syncthreads();
#pragma unroll
    for (int kk = 0; kk < 2; ++kk) {
      bf16x8 af[4];
#pragma unroll
      for (int i = 0; i < 4; ++i)
        af[i] = *(const bf16x8*)&As[(wy * 64 + i * 16 + ml) * 64 + kk * 32 + quad * 8];
#pragma unroll
      for (int j = 0; j < 4; ++j) {
        bf16x8 bfr = *(const bf16x8*)&Bs[(wx * 64 + j * 16 + ml) * 64 + kk * 32 + quad * 8];
#pragma unroll
        for (int i = 0; i < 4; ++i)
          acc[i][j] = __builtin_amdgcn_mfma_f32_16x16x32_bf16(af[i], bfr, acc[i][j], 0, 0, 0);
      }
    }
    __syncthreads();
  }

#pragma unroll
  for (int j = 0; j < 4; ++j) {
    int col = n0 + wx * 64 + j * 16 + ml;
    float bias;
    if (MODE == 0) {
      bias = (col < 4096) ? b0[col] : (col < 4608 ? b1[col - 4096] : b2[col - 4608]);
    } else {
      bias = (col < HID) ? b0[col] : 0.f;
    }
#pragma unroll
    for (int i = 0; i < 4; ++i) {
#pragma unroll
      for (int r = 0; r < 4; ++r) {
        int row = m0 + wy * 64 + i * 16 + quad * 4 + r;
        float v = acc[i][j][r] + bias;
        if (MODE == 0) {
          ((unsigned short*)Cout)[(size_t)row * QKV_N + col] = f2bf(v);
        } else {
          if (col < HID) ((float*)Cout)[(size_t)row * HID + col] = v;
        }
      }
    }
  }
}

// ---------------- sliding-window GQA attention ----------------
// grid (128 q-blocks of 64 rows, 64 heads); block 256
__global__ __launch_bounds__(256) void attn_kernel(
    const unsigned short* __restrict__ qkv, unsigned short* __restrict__ attn) {
  __shared__ unsigned short Qs[64 * 72];    // q rows, stride 72 (pad)
  __shared__ unsigned short Ks[192 * 72];   // ctx keys, stride 72; reused as P[64*200]
  __shared__ unsigned short VTs[64 * 200];  // V transposed: [dim][key], stride 200

  const int tid = threadIdx.x;
  const int B = blockIdx.x;   // 64-row query block
  const int h = blockIdx.y;
  const int hk = h >> 3;
  const int wave = tid >> 6, lane = tid & 63;
  const int quad = lane >> 4, ml = lane & 15;

  // stage Q: 64 rows x 64 cols
#pragma unroll
  for (int it = 0; it < 2; ++it) {
    int s = tid + it * 256;
    int row = s >> 3, c = (s & 7) << 3;
    *(uint4*)&Qs[row * 72 + c] =
        *(const uint4*)(qkv + (size_t)(B * 64 + row) * QKV_N + h * 64 + c);
  }
  // stage K (natural) and V (transposed): 192 ctx rows
#pragma unroll
  for (int it = 0; it < 6; ++it) {
    int s = tid + it * 256;
    int j = s >> 3, c = (s & 7) << 3;
    int tk = B * 64 - 128 + j;
    uint4 kv = make_uint4(0, 0, 0, 0), vv = make_uint4(0, 0, 0, 0);
    if (tk >= 0) {
      kv = *(const uint4*)(qkv + (size_t)tk * QKV_N + 4096 + hk * 64 + c);
      vv = *(const uint4*)(qkv + (size_t)tk * QKV_N + 4608 + hk * 64 + c);
    }
    *(uint4*)&Ks[j * 72 + c] = kv;
    union { uint4 q; unsigned short u[8]; } vu;
    vu.q = vv;
#pragma unroll
    for (int e = 0; e < 8; ++e) VTs[(c + e) * 200 + j] = vu.u[e];
  }
  __syncthreads();

  // scores: wave handles q rows [wave*16, wave*16+16), all 192 ctx cols
  f32x4 zero = {0.f, 0.f, 0.f, 0.f};
  f32x4 sc[12];
#pragma unroll
  for (int jn = 0; jn < 12; ++jn) sc[jn] = zero;
#pragma unroll
  for (int kk = 0; kk < 2; ++kk) {
    bf16x8 af = *(const bf16x8*)&Qs[(wave * 16 + ml) * 72 + kk * 32 + quad * 8];
#pragma unroll
    for (int jn = 0; jn < 12; ++jn) {
      bf16x8 bfr = *(const bf16x8*)&Ks[(jn * 16 + ml) * 72 + kk * 32 + quad * 8];
      sc[jn] = __builtin_amdgcn_mfma_f32_16x16x32_bf16(af, bfr, sc[jn], 0, 0, 0);
    }
  }

  // mask + scale + softmax (rows = wave*16 + quad*4 + r; col = jn*16 + ml)
  const float NEG = -3.0e38f;
  float mx[4], sm[4];
#pragma unroll
  for (int r = 0; r < 4; ++r) mx[r] = NEG;
#pragma unroll
  for (int jn = 0; jn < 12; ++jn) {
    int j = jn * 16 + ml;
#pragma unroll
    for (int r = 0; r < 4; ++r) {
      int i = wave * 16 + quad * 4 + r;
      bool valid = (j > i) && (j <= i + 128) && (B * 64 + j - 128 >= 0);
      float v = valid ? sc[jn][r] * 0.125f : NEG;
      sc[jn][r] = v;
      mx[r] = fmaxf(mx[r], v);
    }
  }
#pragma unroll
  for (int r = 0; r < 4; ++r) {
#pragma unroll
    for (int off = 1; off < 16; off <<= 1)
      mx[r] = fmaxf(mx[r], __shfl_xor(mx[r], off, 64));
    sm[r] = 0.f;
  }
#pragma unroll
  for (int jn = 0; jn < 12; ++jn) {
#pragma unroll
    for (int r = 0; r < 4; ++r) {
      float p = expf(sc[jn][r] - mx[r]);  // masked entries underflow to 0
      sc[jn][r] = p;
      sm[r] += p;
    }
  }
#pragma unroll
  for (int r = 0; r < 4; ++r) {
#pragma unroll
    for (int off = 1; off < 16; off <<= 1) sm[r] += __shfl_xor(sm[r], off, 64);
    sm[r] = 1.0f / sm[r];
  }
  __syncthreads();  // everyone done reading Qs/Ks before P overwrites Ks

  unsigned short* P = Ks;  // overlay: 64 rows, stride 200
#pragma unroll
  for (int jn = 0; jn < 12; ++jn) {
#pragma unroll
    for (int r = 0; r < 4; ++r)
      P[(wave * 16 + quad * 4 + r) * 200 + jn * 16 + ml] = f2bf(sc[jn][r] * sm[r]);
  }
  __syncthreads();

  // PV: O[16 x 64] per wave, K-dim = 192
  f32x4 ov[4];
#pragma unroll
  for (int jn = 0; jn < 4; ++jn) ov[jn] = zero;
#pragma unroll
  for (int ks = 0; ks < 6; ++ks) {
    bf16x8 af = *(const bf16x8*)&P[(wave * 16 + ml) * 200 + ks * 32 + quad * 8];
#pragma unroll
    for (int jn = 0; jn < 4; ++jn) {
      bf16x8 bfr = *(const bf16x8*)&VTs[(jn * 16 + ml) * 200 + ks * 32 + quad * 8];
      ov[jn] = __builtin_amdgcn_mfma_f32_16x16x32_bf16(af, bfr, ov[jn], 0, 0, 0);
    }
  }
#pragma unroll
  for (int jn = 0; jn < 4; ++jn) {
#pragma unroll
    for (int r = 0; r < 4; ++r) {
      int row = B * 64 + wave * 16 + quad * 4 + r;
      attn[(size_t)row * 4096 + h * 64 + jn * 16 + ml] = f2bf(ov[jn][r]);
    }
  }
}

extern "C" void kernel_launch(void* const* d_in, const int* in_sizes, int n_in,
                              void* d_out, int out_size, void* d_ws, size_t ws_size,
                              hipStream_t stream) {
  const float* hidden = (const float*)d_in[0];
  const int* positions = (const int*)d_in[1];
  const float* Wq = (const float*)d_in[2];
  const float* bq = (const float*)d_in[3];
  const float* Wk = (const float*)d_in[4];
  const float* bk = (const float*)d_in[5];
  const float* Wv = (const float*)d_in[6];
  const float* bv = (const float*)d_in[7];
  const float* Wo = (const float*)d_in[8];
  const float* bo = (const float*)d_in[9];
  float* out = (float*)d_out;

  char* ws = (char*)d_ws;
  // layout (bytes):
  //   A_h    @ 0          : 8192*2880*2 = 47,185,920
  //   BTqkv  @ 47185920   : 5120*2880*2 = 29,491,200
  //   qkv    @ 76677120   : 8192*5120*2 = 83,886,080
  //   BTo    @ 160563200  : 2944*4096*2 = 24,117,248   (total 184,680,448)
  //   attn   @ 0          : 8192*4096*2 = 67,108,864   (reuses A_h+BTqkv, both dead)
  unsigned short* A_h   = (unsigned short*)(ws);
  unsigned short* BTqkv = (unsigned short*)(ws + 47185920);
  unsigned short* qkv   = (unsigned short*)(ws + 76677120);
  unsigned short* BTo   = (unsigned short*)(ws + 160563200);
  unsigned short* attn  = (unsigned short*)(ws);

  cvt_bf16_kernel<<<11520, 256, 0, stream>>>(hidden, A_h);  // 8192*2880/8/256
  dim3 tb(32, 8);
  transpose_cvt<<<dim3(128, 90), tb, 0, stream>>>(Wq, BTqkv, HID, 4096, 0);
  transpose_cvt<<<dim3(16, 90), tb, 0, stream>>>(Wk, BTqkv, HID, 512, 4096);
  transpose_cvt<<<dim3(16, 90), tb, 0, stream>>>(Wv, BTqkv, HID, 512, 4608);
  transpose_cvt<<<dim3(90, 128), tb, 0, stream>>>(Wo, BTo, 4096, HID, 0);
  hipMemsetAsync(BTo + (size_t)HID * 4096, 0, (size_t)(NO_PAD - HID) * 4096 * 2, stream);

  gemm_bt<0><<<dim3(QKV_N / 128, S_TOK / 128), 256, 0, stream>>>(
      A_h, BTqkv, qkv, HID, bq, bk, bv);
  rope_kernel<<<73728, 256, 0, stream>>>(qkv, positions);  // 8192*72*32/256
  attn_kernel<<<dim3(S_TOK / 64, NQ), 256, 0, stream>>>(qkv, attn);
  gemm_bt<1><<<dim3(NO_PAD / 128, S_TOK / 128), 256, 0, stream>>>(
      attn, BTo, out, 4096, bo, nullptr, nullptr);
}

// Round 3
// 969.670 us; speedup vs baseline: 1.1193x; 1.1193x over previous
//
#include <hip/hip_runtime.h>
#include <stdint.h>

#define S_TOK 8192
#define HID 2880
#define NQ 64
#define NKV 8
#define HD 64
#define QKV_N 5120   // 4096 q + 512 k + 512 v
#define NO_PAD 2944  // 2880 padded to multiple of 128

typedef __attribute__((ext_vector_type(8))) __bf16 bf16x8;
typedef __attribute__((ext_vector_type(4))) float f32x4;
typedef __attribute__((ext_vector_type(16))) float f32x16;

__device__ __forceinline__ unsigned short f2bf(float f) {
  unsigned int u = __builtin_bit_cast(unsigned int, f);
  u += 0x7fff + ((u >> 16) & 1);
  return (unsigned short)(u >> 16);
}
__device__ __forceinline__ float bf2f(unsigned short h) {
  unsigned int u = ((unsigned int)h) << 16;
  return __builtin_bit_cast(float, u);
}

__device__ __forceinline__ void async_lds16(const void* g, void* l) {
  __builtin_amdgcn_global_load_lds(
      (const __attribute__((address_space(1))) unsigned int*)g,
      (__attribute__((address_space(3))) unsigned int*)l, 16, 0, 0);
}

// ---------------- elementwise f32 -> bf16 ----------------
__global__ __launch_bounds__(256) void cvt_bf16_kernel(
    const float* __restrict__ src, unsigned short* __restrict__ dst) {
  size_t i = ((size_t)blockIdx.x * 256 + threadIdx.x) * 8;
  float4 a = *(const float4*)(src + i);
  float4 b = *(const float4*)(src + i + 4);
  union { unsigned short u[8]; uint4 v; } o;
  o.u[0] = f2bf(a.x); o.u[1] = f2bf(a.y); o.u[2] = f2bf(a.z); o.u[3] = f2bf(a.w);
  o.u[4] = f2bf(b.x); o.u[5] = f2bf(b.y); o.u[6] = f2bf(b.z); o.u[7] = f2bf(b.w);
  *(uint4*)(dst + i) = o.v;
}

// ------------- transpose + convert: src[R][C] f32 -> dst[(c+rowOff)][R] bf16 -------------
__global__ __launch_bounds__(256) void transpose_cvt(
    const float* __restrict__ src, unsigned short* __restrict__ dst,
    int R, int C, int rowOff) {
  __shared__ float tile[32][33];
  int tx = threadIdx.x, ty = threadIdx.y;  // block (32,8)
  int c0 = blockIdx.x * 32, r0 = blockIdx.y * 32;
#pragma unroll
  for (int i = 0; i < 4; ++i)
    tile[ty + i * 8][tx] = src[(size_t)(r0 + ty + i * 8) * C + c0 + tx];
  __syncthreads();
#pragma unroll
  for (int i = 0; i < 4; ++i)
    dst[(size_t)(c0 + ty + i * 8 + rowOff) * R + r0 + tx] = f2bf(tile[tx][ty + i * 8]);
}

// ---------------- in-place RoPE on q (heads 0..63) and k (heads 64..71) ----------------
__global__ __launch_bounds__(256) void rope_kernel(
    unsigned short* __restrict__ qkv, const int* __restrict__ positions) {
  int gid = blockIdx.x * 256 + threadIdx.x;   // 8192*72*32 total
  int d = gid & 31;
  int rest = gid >> 5;
  int head = rest % 72;
  int t = rest / 72;
  unsigned short* p = qkv + (size_t)t * QKV_N + head * 64;
  float x1 = bf2f(p[d]);
  float x2 = bf2f(p[d + 32]);
  float pos = (float)positions[t];
  float inv = exp2f(-0.5373313430f * (float)d);
  float ang = pos * inv;
  float s = sinf(ang), c = cosf(ang);
  p[d] = f2bf(x1 * c - x2 * s);
  p[d + 32] = f2bf(x2 * c + x1 * s);
}

// ---------------- 128x128-tile bf16 GEMM, BT input (rows = N, cols = K) ----------------
// 32x32x16 MFMA, XOR-swizzled LDS (chunk p = c ^ (row&7)) for conflict-free ds_read_b128.
// MODE 0: qkv projection -> bf16 out via LDS repack, 3-segment bias (bq|bk|bv), N=5120
// MODE 1: out projection -> f32 out + bo, valid cols < 2880 (N padded 2944)
template <int MODE>
__global__ __launch_bounds__(256) void gemm_bt(
    const unsigned short* __restrict__ A, const unsigned short* __restrict__ BT,
    void* __restrict__ Cout, int K,
    const float* __restrict__ b0, const float* __restrict__ b1,
    const float* __restrict__ b2) {
  __shared__ unsigned short lds[128 * 128];  // 32 KB; K-loop: As|Bs, epilogue: C tile
  unsigned short* As = lds;            // 128 rows x 8 chunks(16B) swizzled
  unsigned short* Bs = lds + 128 * 64; // 128 rows x 8 chunks swizzled
  const int tid = threadIdx.x;
  const int wave = tid >> 6, lane = tid & 63;
  const int l31 = lane & 31, lh = lane >> 5;
  const int wy = wave >> 1, wx = wave & 1;
  const int m0 = blockIdx.y * 128, n0 = blockIdx.x * 128;

  f32x16 acc[2][2];
#pragma unroll
  for (int i = 0; i < 2; ++i)
#pragma unroll
    for (int j = 0; j < 2; ++j)
#pragma unroll
      for (int r = 0; r < 16; ++r) acc[i][j][r] = 0.f;

  for (int k0 = 0; k0 < K; k0 += 64) {
    const unsigned short* Ag = A + (size_t)m0 * K + k0;
    const unsigned short* Bg = BT + (size_t)n0 * K + k0;
#pragma unroll
    for (int i = 0; i < 4; ++i) {
      int s = tid + i * 256;          // 16B slot in [0,1024)
      int row = s >> 3;
      int c = (s & 7) ^ (row & 7);    // swizzled source chunk
      async_lds16(Ag + (size_t)row * K + c * 8, &As[s * 8]);
      async_lds16(Bg + (size_t)row * K + c * 8, &Bs[s * 8]);
    }
    __syncthreads();
#pragma unroll
    for (int ks = 0; ks < 4; ++ks) {
      bf16x8 af[2], bfr[2];
#pragma unroll
      for (int ra = 0; ra < 2; ++ra) {
        int row = wy * 64 + ra * 32 + l31;
        int p = (ks * 2 + lh) ^ (row & 7);
        af[ra] = *(const bf16x8*)&As[row * 64 + p * 8];
      }
#pragma unroll
      for (int cb = 0; cb < 2; ++cb) {
        int row = wx * 64 + cb * 32 + l31;
        int p = (ks * 2 + lh) ^ (row & 7);
        bfr[cb] = *(const bf16x8*)&Bs[row * 64 + p * 8];
      }
#pragma unroll
      for (int ra = 0; ra < 2; ++ra)
#pragma unroll
        for (int cb = 0; cb < 2; ++cb)
          acc[ra][cb] = __builtin_amdgcn_mfma_f32_32x32x16_bf16(
              af[ra], bfr[cb], acc[ra][cb], 0, 0, 0);
    }
    __syncthreads();
  }

  // C/D layout (32x32): col = lane&31, row = (reg&3) + 8*(reg>>2) + 4*(lane>>5)
  if (MODE == 0) {
#pragma unroll
    for (int cb = 0; cb < 2; ++cb) {
      int col = wx * 64 + cb * 32 + l31;
      int gcol = n0 + col;
      float bias = (gcol < 4096) ? b0[gcol]
                                 : (gcol < 4608 ? b1[gcol - 4096] : b2[gcol - 4608]);
#pragma unroll
      for (int ra = 0; ra < 2; ++ra) {
#pragma unroll
        for (int r = 0; r < 16; ++r) {
          int row = wy * 64 + ra * 32 + (r & 3) + 8 * (r >> 2) + 4 * lh;
          lds[row * 128 + col] = f2bf(acc[ra][cb][r] + bias);
        }
      }
    }
    __syncthreads();
    unsigned short* C16 = (unsigned short*)Cout;
#pragma unroll
    for (int i = 0; i < 8; ++i) {   // 8 * 256 threads * 8 elems = 16384 = full 128x128
      int s = tid + i * 256;
      int row = s >> 4, cc = (s & 15) * 8;
      *(uint4*)(C16 + (size_t)(m0 + row) * QKV_N + n0 + cc) =
          *(const uint4*)&lds[row * 128 + cc];
    }
  } else {
#pragma unroll
    for (int cb = 0; cb < 2; ++cb) {
      int gcol = n0 + wx * 64 + cb * 32 + l31;
      if (gcol < HID) {
        float bias = b0[gcol];
#pragma unroll
        for (int ra = 0; ra < 2; ++ra) {
#pragma unroll
          for (int r = 0; r < 16; ++r) {
            int row = m0 + wy * 64 + ra * 32 + (r & 3) + 8 * (r >> 2) + 4 * lh;
            ((float*)Cout)[(size_t)row * HID + gcol] = acc[ra][cb][r] + bias;
          }
        }
      }
    }
  }
}

// ---------------- sliding-window GQA attention ----------------
// grid (128 q-blocks of 64 rows, 64 heads); block 256
__global__ __launch_bounds__(256) void attn_kernel(
    const unsigned short* __restrict__ qkv, unsigned short* __restrict__ attn) {
  __shared__ unsigned short Qs[64 * 72];    // q rows, stride 72 (pad)
  __shared__ unsigned short Ks[192 * 72];   // ctx keys, stride 72; reused as P[64*200]
  __shared__ unsigned short VTs[64 * 200];  // V transposed: [dim][key], stride 200

  const int tid = threadIdx.x;
  const int B = blockIdx.x;   // 64-row query block
  const int h = blockIdx.y;
  const int hk = h >> 3;
  const int wave = tid >> 6, lane = tid & 63;
  const int quad = lane >> 4, ml = lane & 15;

  // stage Q: 64 rows x 64 cols
#pragma unroll
  for (int it = 0; it < 2; ++it) {
    int s = tid + it * 256;
    int row = s >> 3, c = (s & 7) << 3;
    *(uint4*)&Qs[row * 72 + c] =
        *(const uint4*)(qkv + (size_t)(B * 64 + row) * QKV_N + h * 64 + c);
  }
  // stage K (natural) and V (transposed): 192 ctx rows
#pragma unroll
  for (int it = 0; it < 6; ++it) {
    int s = tid + it * 256;
    int j = s >> 3, c = (s & 7) << 3;
    int tk = B * 64 - 128 + j;
    uint4 kv = make_uint4(0, 0, 0, 0), vv = make_uint4(0, 0, 0, 0);
    if (tk >= 0) {
      kv = *(const uint4*)(qkv + (size_t)tk * QKV_N + 4096 + hk * 64 + c);
      vv = *(const uint4*)(qkv + (size_t)tk * QKV_N + 4608 + hk * 64 + c);
    }
    *(uint4*)&Ks[j * 72 + c] = kv;
    union { uint4 q; unsigned short u[8]; } vu;
    vu.q = vv;
#pragma unroll
    for (int e = 0; e < 8; ++e) VTs[(c + e) * 200 + j] = vu.u[e];
  }
  __syncthreads();

  // scores: wave handles q rows [wave*16, wave*16+16), all 192 ctx cols
  f32x4 zero = {0.f, 0.f, 0.f, 0.f};
  f32x4 sc[12];
#pragma unroll
  for (int jn = 0; jn < 12; ++jn) sc[jn] = zero;
#pragma unroll
  for (int kk = 0; kk < 2; ++kk) {
    bf16x8 af = *(const bf16x8*)&Qs[(wave * 16 + ml) * 72 + kk * 32 + quad * 8];
#pragma unroll
    for (int jn = 0; jn < 12; ++jn) {
      bf16x8 bfr = *(const bf16x8*)&Ks[(jn * 16 + ml) * 72 + kk * 32 + quad * 8];
      sc[jn] = __builtin_amdgcn_mfma_f32_16x16x32_bf16(af, bfr, sc[jn], 0, 0, 0);
    }
  }

  // mask + scale + softmax (rows = wave*16 + quad*4 + r; col = jn*16 + ml)
  const float NEG = -3.0e38f;
  float mx[4], sm[4];
#pragma unroll
  for (int r = 0; r < 4; ++r) mx[r] = NEG;
#pragma unroll
  for (int jn = 0; jn < 12; ++jn) {
    int j = jn * 16 + ml;
#pragma unroll
    for (int r = 0; r < 4; ++r) {
      int i = wave * 16 + quad * 4 + r;
      bool valid = (j > i) && (j <= i + 128) && (B * 64 + j - 128 >= 0);
      float v = valid ? sc[jn][r] * 0.125f : NEG;
      sc[jn][r] = v;
      mx[r] = fmaxf(mx[r], v);
    }
  }
#pragma unroll
  for (int r = 0; r < 4; ++r) {
#pragma unroll
    for (int off = 1; off < 16; off <<= 1)
      mx[r] = fmaxf(mx[r], __shfl_xor(mx[r], off, 64));
    sm[r] = 0.f;
  }
#pragma unroll
  for (int jn = 0; jn < 12; ++jn) {
#pragma unroll
    for (int r = 0; r < 4; ++r) {
      float p = expf(sc[jn][r] - mx[r]);  // masked entries underflow to 0
      sc[jn][r] = p;
      sm[r] += p;
    }
  }
#pragma unroll
  for (int r = 0; r < 4; ++r) {
#pragma unroll
    for (int off = 1; off < 16; off <<= 1) sm[r] += __shfl_xor(sm[r], off, 64);
    sm[r] = 1.0f / sm[r];
  }
  __syncthreads();  // everyone done reading Qs/Ks before P overwrites Ks

  unsigned short* P = Ks;  // overlay: 64 rows, stride 200
#pragma unroll
  for (int jn = 0; jn < 12; ++jn) {
#pragma unroll
    for (int r = 0; r < 4; ++r)
      P[(wave * 16 + quad * 4 + r) * 200 + jn * 16 + ml] = f2bf(sc[jn][r] * sm[r]);
  }
  __syncthreads();

  // PV: O[16 x 64] per wave, K-dim = 192
  f32x4 ov[4];
#pragma unroll
  for (int jn = 0; jn < 4; ++jn) ov[jn] = zero;
#pragma unroll
  for (int ks = 0; ks < 6; ++ks) {
    bf16x8 af = *(const bf16x8*)&P[(wave * 16 + ml) * 200 + ks * 32 + quad * 8];
#pragma unroll
    for (int jn = 0; jn < 4; ++jn) {
      bf16x8 bfr = *(const bf16x8*)&VTs[(jn * 16 + ml) * 200 + ks * 32 + quad * 8];
      ov[jn] = __builtin_amdgcn_mfma_f32_16x16x32_bf16(af, bfr, ov[jn], 0, 0, 0);
    }
  }
#pragma unroll
  for (int jn = 0; jn < 4; ++jn) {
#pragma unroll
    for (int r = 0; r < 4; ++r) {
      int row = B * 64 + wave * 16 + quad * 4 + r;
      attn[(size_t)row * 4096 + h * 64 + jn * 16 + ml] = f2bf(ov[jn][r]);
    }
  }
}

extern "C" void kernel_launch(void* const* d_in, const int* in_sizes, int n_in,
                              void* d_out, int out_size, void* d_ws, size_t ws_size,
                              hipStream_t stream) {
  const float* hidden = (const float*)d_in[0];
  const int* positions = (const int*)d_in[1];
  const float* Wq = (const float*)d_in[2];
  const float* bq = (const float*)d_in[3];
  const float* Wk = (const float*)d_in[4];
  const float* bk = (const float*)d_in[5];
  const float* Wv = (const float*)d_in[6];
  const float* bv = (const float*)d_in[7];
  const float* Wo = (const float*)d_in[8];
  const float* bo = (const float*)d_in[9];
  float* out = (float*)d_out;

  char* ws = (char*)d_ws;
  unsigned short* A_h   = (unsigned short*)(ws);
  unsigned short* BTqkv = (unsigned short*)(ws + 47185920);
  unsigned short* qkv   = (unsigned short*)(ws + 76677120);
  unsigned short* BTo   = (unsigned short*)(ws + 160563200);
  unsigned short* attn  = (unsigned short*)(ws);

  cvt_bf16_kernel<<<11520, 256, 0, stream>>>(hidden, A_h);
  dim3 tb(32, 8);
  transpose_cvt<<<dim3(128, 90), tb, 0, stream>>>(Wq, BTqkv, HID, 4096, 0);
  transpose_cvt<<<dim3(16, 90), tb, 0, stream>>>(Wk, BTqkv, HID, 512, 4096);
  transpose_cvt<<<dim3(16, 90), tb, 0, stream>>>(Wv, BTqkv, HID, 512, 4608);
  transpose_cvt<<<dim3(90, 128), tb, 0, stream>>>(Wo, BTo, 4096, HID, 0);
  hipMemsetAsync(BTo + (size_t)HID * 4096, 0, (size_t)(NO_PAD - HID) * 4096 * 2, stream);

  gemm_bt<0><<<dim3(QKV_N / 128, S_TOK / 128), 256, 0, stream>>>(
      A_h, BTqkv, qkv, HID, bq, bk, bv);
  rope_kernel<<<73728, 256, 0, stream>>>(qkv, positions);
  attn_kernel<<<dim3(S_TOK / 64, NQ), 256, 0, stream>>>(qkv, attn);
  gemm_bt<1><<<dim3(NO_PAD / 128, S_TOK / 128), 256, 0, stream>>>(
      attn, BTo, out, 4096, bo, nullptr, nullptr);
}